// Round 18
// baseline (60.361 us; speedup 1.0000x reference)
//
#include <hip/hip_runtime.h>
#include <stdint.h>

typedef __bf16 bf16_t;
typedef __bf16 bf16x8 __attribute__((ext_vector_type(8)));
typedef float f32x4 __attribute__((ext_vector_type(4)));
typedef unsigned short ushort8 __attribute__((ext_vector_type(8)));

#define M_DIM 16384
#define N_DIM 1024
#define K_DIM 1024
#define BM 256
#define BN 256
#define BK 64
#define NT (K_DIM / BK)          // 16 K-tiles, 8 iterations x 2 tiles
// LDS: 2 buffers x 64 KB; buffer = {Ah0,Ah1,Bh0,Bh1} x 16 KB regions
#define BUF_B 65536
#define B_OFF 32768

// ---------------- x: f32 -> bf16 (RNE), vectorized ----------------
__global__ void cvt_x_bf16(const float* __restrict__ x,
                           unsigned short* __restrict__ xb, int n8) {
    int i = blockIdx.x * blockDim.x + threadIdx.x;
    int stride = gridDim.x * blockDim.x;
    for (; i < n8; i += stride) {
        const float4* p = (const float4*)(x + (size_t)i * 8);
        float4 v0 = p[0], v1 = p[1];
        float vv[8] = {v0.x, v0.y, v0.z, v0.w, v1.x, v1.y, v1.z, v1.w};
        ushort8 o;
#pragma unroll
        for (int j = 0; j < 8; ++j) {
            uint32_t u = __builtin_bit_cast(uint32_t, vv[j]);
            u = u + 0x7FFFu + ((u >> 16) & 1u);   // round-to-nearest-even
            o[j] = (unsigned short)(u >> 16);
        }
        *(ushort8*)(xb + (size_t)i * 8) = o;
    }
}

// ------- W: binarize (exact reference semantics) + transpose to [N][K] -------
__global__ void bin_transpose_w(const float* __restrict__ W,
                                unsigned short* __restrict__ WbT) {
    __shared__ unsigned short t[64][68];
    int tj = blockIdx.x;                   // n tile
    int ti = blockIdx.y;                   // k tile
    int tid = threadIdx.x;
    int c4 = (tid & 15) * 4;
    int r0 = tid >> 4;
#pragma unroll
    for (int p = 0; p < 4; ++p) {
        int r = r0 + p * 16;
        float4 v = *(const float4*)(W + (size_t)(ti * 64 + r) * N_DIM + tj * 64 + c4);
        // reference: +1 iff (w+1)/2 > 0.5 (round-half-even at exactly 0.5 -> -1)
        t[r][c4 + 0] = ((v.x + 1.0f) * 0.5f > 0.5f) ? 0x3F80 : 0xBF80;
        t[r][c4 + 1] = ((v.y + 1.0f) * 0.5f > 0.5f) ? 0x3F80 : 0xBF80;
        t[r][c4 + 2] = ((v.z + 1.0f) * 0.5f > 0.5f) ? 0x3F80 : 0xBF80;
        t[r][c4 + 3] = ((v.w + 1.0f) * 0.5f > 0.5f) ? 0x3F80 : 0xBF80;
    }
    __syncthreads();
#pragma unroll
    for (int p = 0; p < 4; ++p) {
        int rn = r0 + p * 16;
        ushort4 o;
        o.x = t[c4 + 0][rn];
        o.y = t[c4 + 1][rn];
        o.z = t[c4 + 2][rn];
        o.w = t[c4 + 3][rn];
        *(ushort4*)(WbT + (size_t)(tj * 64 + rn) * K_DIM + ti * 64 + c4) = o;
    }
}

// ---------------- 8-phase (m201-template) bf16 GEMM ----------------
__device__ __forceinline__ void gload16(const void* g, const void* l) {
    __builtin_amdgcn_global_load_lds(
        (const __attribute__((address_space(1))) void*)(g),
        (__attribute__((address_space(3))) void*)(l),
        16, 0, 0);
}

__global__ __launch_bounds__(512, 2) void bgemm(const bf16_t* __restrict__ A,
                                                const bf16_t* __restrict__ Bt,
                                                const float* __restrict__ bias,
                                                float* __restrict__ C) {
    __shared__ __align__(16) char lds[2 * BUF_B];   // 128 KB

    const int nwg = (M_DIM / BM) * (N_DIM / BN);   // 256, %8==0
    int bid = blockIdx.x;
    int swz = (bid & 7) * (nwg >> 3) + (bid >> 3); // XCD-aware, bijective
    int tile_n = swz & 3;                          // consecutive swz share A panel
    int tile_m = swz >> 2;
    int bm0 = tile_m * BM;
    int bn0 = tile_n * BN;

    int tid = threadIdx.x;
    int w = tid >> 6, l = tid & 63;    // 8 waves: 2(M) x 4(N)
    int wr = w >> 2, wc = w & 3;       // per-wave 128x64 output
    int lr = l & 15, lk = l >> 4, l7 = l & 7;

    // staging: linear LDS dest (tid*16); R4/R6-proven 128B-row swizzle via
    // pre-swizzled per-lane global source chunk (both-sides rule)
    int srow = tid >> 3;                         // 0..63 per call
    int schunk = (tid & 7) ^ (srow & 7);
    // half-tile stagers: h = which 128-row half, 2 gload calls each
    auto stageAh = [&](int t, int h) {
#pragma unroll
        for (int c = 0; c < 2; ++c)
            gload16(A + (size_t)(bm0 + h * 128 + c * 64 + srow) * K_DIM
                        + t * BK + schunk * 8,
                    lds + (t & 1) * BUF_B + h * 16384 + c * 8192 + tid * 16);
    };
    auto stageBh = [&](int t, int h) {
#pragma unroll
        for (int c = 0; c < 2; ++c)
            gload16(Bt + (size_t)(bn0 + h * 128 + c * 64 + srow) * K_DIM
                         + t * BK + schunk * 8,
                    lds + (t & 1) * BUF_B + B_OFF + h * 16384 + c * 8192 + tid * 16);
    };

    f32x4 acc[8][4];
#pragma unroll
    for (int m = 0; m < 8; ++m)
#pragma unroll
        for (int n = 0; n < 4; ++n)
            acc[m][n] = (f32x4)(0.0f);

    bf16x8 bfr[4][2];   // B frags persist across each tile's 4 phases

    // one phase: 4 A ds_reads (+8 B at PP==0) | stage | barrier | 16 MFMA | barrier
#define PHASE(TILE, PP, STAGE, WAIT)                                            \
    {                                                                           \
        const char* Ar = lds + ((TILE) & 1) * BUF_B + wr * 16384;               \
        bf16x8 afr[2][2];                                                       \
        _Pragma("unroll") for (int i = 0; i < 2; ++i)                           \
            _Pragma("unroll") for (int kk = 0; kk < 2; ++kk)                    \
                afr[i][kk] = *(const bf16x8*)(Ar + (((PP) * 2 + i) * 16 + lr) * 128 \
                                              + (((kk * 4 + lk) ^ l7) * 16));   \
        if ((PP) == 0) {                                                        \
            const char* Br = lds + ((TILE) & 1) * BUF_B + B_OFF + (wc >> 1) * 16384; \
            _Pragma("unroll") for (int n = 0; n < 4; ++n)                       \
                _Pragma("unroll") for (int kk = 0; kk < 2; ++kk)                \
                    bfr[n][kk] = *(const bf16x8*)(Br + ((wc & 1) * 64 + n * 16 + lr) * 128 \
                                                  + (((kk * 4 + lk) ^ l7) * 16)); \
        }                                                                       \
        STAGE;                                                                  \
        if ((PP) == 0) asm volatile("s_waitcnt lgkmcnt(8)" ::: "memory");       \
        __builtin_amdgcn_s_barrier();                                           \
        asm volatile("s_waitcnt lgkmcnt(0)" ::: "memory");                      \
        __builtin_amdgcn_sched_barrier(0);                                      \
        __builtin_amdgcn_s_setprio(1);                                          \
        _Pragma("unroll") for (int i = 0; i < 2; ++i)                           \
            _Pragma("unroll") for (int n = 0; n < 4; ++n)                       \
                _Pragma("unroll") for (int kk = 0; kk < 2; ++kk)                \
                    acc[(PP) * 2 + i][n] = __builtin_amdgcn_mfma_f32_16x16x32_bf16( \
                        afr[i][kk], bfr[n][kk], acc[(PP) * 2 + i][n], 0, 0, 0); \
        __builtin_amdgcn_s_setprio(0);                                          \
        WAIT;                                                                   \
        __builtin_amdgcn_s_barrier();                                           \
    }

    // ---- prologue: A(0),B(0) fully + B(1); retire tile 0, keep B(1) flying ----
    stageAh(0, 0); stageAh(0, 1);
    stageBh(0, 0); stageBh(0, 1);
    stageBh(1, 0); stageBh(1, 1);
    asm volatile("s_waitcnt vmcnt(4)" ::: "memory");
    __builtin_amdgcn_s_barrier();

    for (int it = 0; it < NT / 2; ++it) {
        int t0 = it * 2, t1 = t0 + 1;
        bool pf0 = (t0 + 2) < NT, pf1 = (t1 + 2) < NT;

        // tile t0 (buf 0); staging rotation fills regions freed 4-7 phases ago
        PHASE(t0, 0, stageAh(t1, 0), );
        PHASE(t0, 1, stageAh(t1, 1), );
        PHASE(t0, 2, if (pf0) stageBh(t0 + 2, 0), );
        PHASE(t0, 3, if (pf0) stageBh(t0 + 2, 1),
              if (pf0) asm volatile("s_waitcnt vmcnt(4)" ::: "memory");
              else     asm volatile("s_waitcnt vmcnt(0)" ::: "memory"););
        // tile t1 (buf 1)
        PHASE(t1, 0, if (pf0) stageAh(t0 + 2, 0), );
        PHASE(t1, 1, if (pf0) stageAh(t0 + 2, 1), );
        PHASE(t1, 2, if (pf1) stageBh(t1 + 2, 0), );
        PHASE(t1, 3, if (pf1) stageBh(t1 + 2, 1),
              if (pf1) asm volatile("s_waitcnt vmcnt(4)" ::: "memory"););
    }
#undef PHASE

    // ---- epilogue: C/D layout col = lane&15, row = (lane>>4)*4 + reg ----
#pragma unroll
    for (int n = 0; n < 4; ++n) {
        int col = bn0 + wc * 64 + n * 16 + lr;
        float bv = bias[col];
#pragma unroll
        for (int m = 0; m < 8; ++m) {
            int row0 = bm0 + wr * 128 + m * 16 + lk * 4;
#pragma unroll
            for (int j = 0; j < 4; ++j)
                C[(size_t)(row0 + j) * N_DIM + col] = acc[m][n][j] + bv;
        }
    }
}

// ---------------- fallback (only if workspace too small) ----------------
__global__ void naive_bin_dense(const float* __restrict__ x,
                                const float* __restrict__ W,
                                const float* __restrict__ b,
                                float* __restrict__ out) {
    int col = blockIdx.x * 256 + threadIdx.x;
    int row = blockIdx.y;
    float acc = 0.0f;
    for (int k = 0; k < K_DIM; ++k) {
        float s = ((W[(size_t)k * N_DIM + col] + 1.0f) * 0.5f > 0.5f) ? 1.0f : -1.0f;
        acc += x[(size_t)row * K_DIM + k] * s;
    }
    out[(size_t)row * N_DIM + col] = acc + b[col];
}

extern "C" void kernel_launch(void* const* d_in, const int* in_sizes, int n_in,
                              void* d_out, int out_size, void* d_ws, size_t ws_size,
                              hipStream_t stream) {
    const float* x = (const float*)d_in[0];
    const float* W = (const float*)d_in[1];
    const float* b = (const float*)d_in[2];
    float* out = (float*)d_out;

    size_t xb_bytes = (size_t)M_DIM * K_DIM * sizeof(unsigned short);
    size_t wb_bytes = (size_t)K_DIM * N_DIM * sizeof(unsigned short);

    if (ws_size >= xb_bytes + wb_bytes) {
        unsigned short* xb = (unsigned short*)d_ws;
        unsigned short* wbt = (unsigned short*)((char*)d_ws + xb_bytes);
        hipLaunchKernelGGL(bin_transpose_w, dim3(N_DIM / 64, K_DIM / 64), dim3(256),
                           0, stream, W, wbt);
        hipLaunchKernelGGL(cvt_x_bf16, dim3(2048), dim3(256), 0, stream,
                           x, xb, (M_DIM * K_DIM) / 8);
        hipLaunchKernelGGL(bgemm, dim3((M_DIM / BM) * (N_DIM / BN)), dim3(512), 0, stream,
                           (const bf16_t*)xb, (const bf16_t*)wbt, b, out);
    } else {
        hipLaunchKernelGGL(naive_bin_dense, dim3(N_DIM / 256, M_DIM), dim3(256),
                           0, stream, x, W, b, out);
    }
}

// Round 19
// 50.999 us; speedup vs baseline: 1.1836x; 1.1836x over previous
//
#include <hip/hip_runtime.h>
#include <stdint.h>

typedef __bf16 bf16_t;
typedef __bf16 bf16x8 __attribute__((ext_vector_type(8)));
typedef float f32x4 __attribute__((ext_vector_type(4)));

#define M_DIM 16384
#define N_DIM 1024
#define K_DIM 1024
#define BM 128
#define BN 256
#define BK 32
#define NT (K_DIM / BK)          // 32 K-tiles (even)
#define A_SLOT 8192              // bytes: 128 rows x 64B (bf16)
#define B_SLOT 16384             // bytes: 256 rows x 64B (bf16)
#define B_BASE 16384             // after 2 A slots
// LDS: A[2] + B[2] = 48 KB -> 2 blocks/CU

// ------- W: binarize (exact reference semantics) + transpose to [N][K] -------
__global__ void bin_transpose_w(const float* __restrict__ W,
                                unsigned short* __restrict__ WbT) {
    __shared__ unsigned short t[64][68];
    int tj = blockIdx.x;                   // n tile
    int ti = blockIdx.y;                   // k tile
    int tid = threadIdx.x;
    int c4 = (tid & 15) * 4;
    int r0 = tid >> 4;
#pragma unroll
    for (int p = 0; p < 4; ++p) {
        int r = r0 + p * 16;
        float4 v = *(const float4*)(W + (size_t)(ti * 64 + r) * N_DIM + tj * 64 + c4);
        // reference: +1 iff (w+1)/2 > 0.5 (round-half-even at exactly 0.5 -> -1)
        t[r][c4 + 0] = ((v.x + 1.0f) * 0.5f > 0.5f) ? 0x3F80 : 0xBF80;
        t[r][c4 + 1] = ((v.y + 1.0f) * 0.5f > 0.5f) ? 0x3F80 : 0xBF80;
        t[r][c4 + 2] = ((v.z + 1.0f) * 0.5f > 0.5f) ? 0x3F80 : 0xBF80;
        t[r][c4 + 3] = ((v.w + 1.0f) * 0.5f > 0.5f) ? 0x3F80 : 0xBF80;
    }
    __syncthreads();
#pragma unroll
    for (int p = 0; p < 4; ++p) {
        int rn = r0 + p * 16;
        ushort4 o;
        o.x = t[c4 + 0][rn];
        o.y = t[c4 + 1][rn];
        o.z = t[c4 + 2][rn];
        o.w = t[c4 + 3][rn];
        *(ushort4*)(WbT + (size_t)(tj * 64 + rn) * K_DIM + ti * 64 + c4) = o;
    }
}

// ------- fused GEMM: A global->reg->cvt->LDS(bf16), 2-deep; B gload_lds -------
__device__ __forceinline__ void gload16(const void* g, const void* l) {
    __builtin_amdgcn_global_load_lds(
        (const __attribute__((address_space(1))) void*)(g),
        (__attribute__((address_space(3))) void*)(l),
        16, 0, 0);
}

__global__ __launch_bounds__(512, 4) void bgemm(const float* __restrict__ X,
                                                const bf16_t* __restrict__ Bt,
                                                const float* __restrict__ bias,
                                                float* __restrict__ C) {
    __shared__ __align__(16) char lds[2 * A_SLOT + 2 * B_SLOT];   // 48 KB

    const int nwg = (M_DIM / BM) * (N_DIM / BN);   // 512, %8==0
    int bid = blockIdx.x;
    int swz = (bid & 7) * (nwg >> 3) + (bid >> 3); // XCD-aware, bijective
    int tile_n = swz & 3;                          // consecutive swz share A panel
    int tile_m = swz >> 2;
    int bm0 = tile_m * BM;
    int bn0 = tile_n * BN;

    int tid = threadIdx.x;
    int w = tid >> 6, l = tid & 63;    // 8 waves: 2(M) x 4(N)
    int wr = w >> 2, wc = w & 3;       // per-wave 64x64 output
    int lr = l & 15, lk = l >> 4;

    // ---- A: thread owns row ar (0..127), 32B f32 chunk ac (0..3) ----
    int ar = tid >> 2, ac = tid & 3;
    int aslot = ac ^ ((ar >> 1) & 3);              // proven-zero write swizzle
    const float* asrc = X + (size_t)(bm0 + ar) * K_DIM + ac * 8;

    // ---- B staging: gload_lds, linear dest, pre-swizzled source (proven) ----
    int brow = tid >> 2;
    int bchk = (tid & 3) ^ ((brow >> 1) & 3);
    auto stageB = [&](int t, int c) {
        gload16(Bt + (size_t)(bn0 + c * 128 + brow) * K_DIM + t * BK + bchk * 8,
                lds + B_BASE + (t & 1) * B_SLOT + c * 8192 + tid * 16);
    };
    auto writeA = [&](int t, float4 lo, float4 hi) {   // cvt RNE + 1 ds_write_b128
        bf16x8 v;
        v[0] = (__bf16)lo.x; v[1] = (__bf16)lo.y;
        v[2] = (__bf16)lo.z; v[3] = (__bf16)lo.w;
        v[4] = (__bf16)hi.x; v[5] = (__bf16)hi.y;
        v[6] = (__bf16)hi.z; v[7] = (__bf16)hi.w;
        *(bf16x8*)(lds + (t & 1) * A_SLOT + ar * 64 + aslot * 16) = v;
    };

    f32x4 acc[4][4];
#pragma unroll
    for (int m = 0; m < 4; ++m)
#pragma unroll
        for (int n = 0; n < 4; ++n)
            acc[m][n] = (f32x4)(0.0f);

    // two named A-reg sets: A(k) lives in set k&1 (static indexing, rule #20)
    float4 aL0, aH0, aL1, aH1;

    // ---- prologue ----
    { const float4* s = (const float4*)(asrc + 0 * BK); aL0 = s[0]; aH0 = s[1]; }
    stageB(0, 0); stageB(0, 1);
    { const float4* s = (const float4*)(asrc + 1 * BK); aL1 = s[0]; aH1 = s[1]; }
    writeA(0, aL0, aH0);                       // implicit wait on A(0) regs
    asm volatile("s_waitcnt vmcnt(2)" ::: "memory");   // B(0) RESIDENT; A(1) flies
    asm volatile("s_waitcnt lgkmcnt(0)" ::: "memory"); // A(0) write visible
    __builtin_amdgcn_s_barrier();

    // ---- main loop, unrolled x2 for static A-reg set selection ----
    // top of tile t: writeA(t+1) (slot (t+1)&1 free: tile t-1's reads retired at
    // the barrier); then issue B(t+1), A(t+2); compute; boundary vmcnt(2) retires
    // B(t+1), keeps A(t+2) in flight (T4); lgkmcnt(0) free (write long drained).
#define TILE_BODY(T, CUR_L, CUR_H, NXT_L, NXT_H)                                  \
    {                                                                             \
        const int t_ = (T);                                                       \
        if (t_ + 1 < NT)                                                          \
            writeA(t_ + 1, NXT_L, NXT_H);      /* implicit wait on A(t+1) regs */ \
        if (t_ + 1 < NT) { stageB(t_ + 1, 0); stageB(t_ + 1, 1); }                \
        if (t_ + 2 < NT) {                                                        \
            const float4* s = (const float4*)(asrc + (t_ + 2) * BK);              \
            CUR_L = s[0]; CUR_H = s[1];        /* set (t+2)&1 == t&1 */           \
        }                                                                         \
        const char* Ab = lds + (t_ & 1) * A_SLOT;                                 \
        const char* Bb = lds + B_BASE + (t_ & 1) * B_SLOT;                        \
        bf16x8 bfr[4];                                                            \
        _Pragma("unroll") for (int n = 0; n < 4; ++n) {                           \
            int br = wc * 64 + n * 16 + lr;                                       \
            bfr[n] = *(const bf16x8*)(Bb + br * 64 + ((lk ^ ((br >> 1) & 3)) * 16)); \
        }                                                                         \
        _Pragma("unroll") for (int m = 0; m < 4; ++m) {                           \
            int r = wr * 64 + m * 16 + lr;                                        \
            bf16x8 afr = *(const bf16x8*)(Ab + r * 64 + ((lk ^ ((r >> 1) & 3)) * 16)); \
            _Pragma("unroll") for (int n = 0; n < 4; ++n)                         \
                acc[m][n] = __builtin_amdgcn_mfma_f32_16x16x32_bf16(              \
                    afr, bfr[n], acc[m][n], 0, 0, 0);                             \
        }                                                                         \
        if (t_ + 1 < NT) {                                                        \
            if (t_ + 2 < NT)                                                      \
                asm volatile("s_waitcnt vmcnt(2)" ::: "memory"); /* B(t+1) res. */ \
            else                                                                  \
                asm volatile("s_waitcnt vmcnt(0)" ::: "memory");                  \
            asm volatile("s_waitcnt lgkmcnt(0)" ::: "memory");                    \
            __builtin_amdgcn_s_barrier();                                         \
        }                                                                         \
    }

    for (int tt = 0; tt < NT; tt += 2) {
        TILE_BODY(tt,     aL0, aH0, aL1, aH1);   // even t: load->set0, write set1
        TILE_BODY(tt + 1, aL1, aH1, aL0, aH0);   // odd  t: load->set1, write set0
    }
#undef TILE_BODY

    // ---- epilogue: C/D layout col = lane&15, row = (lane>>4)*4 + reg ----
#pragma unroll
    for (int n = 0; n < 4; ++n) {
        int col = bn0 + wc * 64 + n * 16 + lr;
        float bv = bias[col];
#pragma unroll
        for (int m = 0; m < 4; ++m) {
            int row0 = bm0 + wr * 64 + m * 16 + lk * 4;
#pragma unroll
            for (int j = 0; j < 4; ++j)
                C[(size_t)(row0 + j) * N_DIM + col] = acc[m][n][j] + bv;
        }
    }
}

// ---------------- fallback (only if workspace too small) ----------------
__global__ void naive_bin_dense(const float* __restrict__ x,
                                const float* __restrict__ W,
                                const float* __restrict__ b,
                                float* __restrict__ out) {
    int col = blockIdx.x * 256 + threadIdx.x;
    int row = blockIdx.y;
    float acc = 0.0f;
    for (int k = 0; k < K_DIM; ++k) {
        float s = ((W[(size_t)k * N_DIM + col] + 1.0f) * 0.5f > 0.5f) ? 1.0f : -1.0f;
        acc += x[(size_t)row * K_DIM + k] * s;
    }
    out[(size_t)row * N_DIM + col] = acc + b[col];
}

extern "C" void kernel_launch(void* const* d_in, const int* in_sizes, int n_in,
                              void* d_out, int out_size, void* d_ws, size_t ws_size,
                              hipStream_t stream) {
    const float* x = (const float*)d_in[0];
    const float* W = (const float*)d_in[1];
    const float* b = (const float*)d_in[2];
    float* out = (float*)d_out;

    size_t wb_bytes = (size_t)K_DIM * N_DIM * sizeof(unsigned short);

    if (ws_size >= wb_bytes) {
        unsigned short* wbt = (unsigned short*)d_ws;
        hipLaunchKernelGGL(bin_transpose_w, dim3(N_DIM / 64, K_DIM / 64), dim3(256),
                           0, stream, W, wbt);
        hipLaunchKernelGGL(bgemm, dim3((M_DIM / BM) * (N_DIM / BN)), dim3(512), 0, stream,
                           x, (const bf16_t*)wbt, b, out);
    } else {
        hipLaunchKernelGGL(naive_bin_dense, dim3(N_DIM / 256, M_DIM), dim3(256),
                           0, stream, x, W, b, out);
    }
}

// Round 20
// 49.460 us; speedup vs baseline: 1.2204x; 1.0311x over previous
//
#include <hip/hip_runtime.h>
#include <stdint.h>

typedef __bf16 bf16_t;
typedef __bf16 bf16x8 __attribute__((ext_vector_type(8)));
typedef float f32x4 __attribute__((ext_vector_type(4)));

#define M_DIM 16384
#define N_DIM 1024
#define K_DIM 1024
#define BM 128
#define BN 256
#define BK 32
#define NT (K_DIM / BK)          // 32 K-tiles (even)
#define A_SLOT 8192              // bytes: 128 rows x 64B (bf16)
#define B_SLOT 16384             // bytes: 256 rows x 64B (bf16)
#define B_BASE 16384             // after 2 A slots
// LDS: A[2] + B[2] = 48 KB -> 2 blocks/CU

// ------- W: binarize (exact reference semantics) + transpose to [N][K] -------
__global__ void bin_transpose_w(const float* __restrict__ W,
                                unsigned short* __restrict__ WbT) {
    __shared__ unsigned short t[64][68];
    int tj = blockIdx.x;                   // n tile
    int ti = blockIdx.y;                   // k tile
    int tid = threadIdx.x;
    int c4 = (tid & 15) * 4;
    int r0 = tid >> 4;
#pragma unroll
    for (int p = 0; p < 4; ++p) {
        int r = r0 + p * 16;
        float4 v = *(const float4*)(W + (size_t)(ti * 64 + r) * N_DIM + tj * 64 + c4);
        // reference: +1 iff (w+1)/2 > 0.5 (round-half-even at exactly 0.5 -> -1)
        t[r][c4 + 0] = ((v.x + 1.0f) * 0.5f > 0.5f) ? 0x3F80 : 0xBF80;
        t[r][c4 + 1] = ((v.y + 1.0f) * 0.5f > 0.5f) ? 0x3F80 : 0xBF80;
        t[r][c4 + 2] = ((v.z + 1.0f) * 0.5f > 0.5f) ? 0x3F80 : 0xBF80;
        t[r][c4 + 3] = ((v.w + 1.0f) * 0.5f > 0.5f) ? 0x3F80 : 0xBF80;
    }
    __syncthreads();
#pragma unroll
    for (int p = 0; p < 4; ++p) {
        int rn = r0 + p * 16;
        ushort4 o;
        o.x = t[c4 + 0][rn];
        o.y = t[c4 + 1][rn];
        o.z = t[c4 + 2][rn];
        o.w = t[c4 + 3][rn];
        *(ushort4*)(WbT + (size_t)(tj * 64 + rn) * K_DIM + ti * 64 + c4) = o;
    }
}

// ------- fused GEMM: A global->reg->cvt->LDS(bf16), 2-deep; B gload_lds -------
__device__ __forceinline__ void gload16(const void* g, const void* l) {
    __builtin_amdgcn_global_load_lds(
        (const __attribute__((address_space(1))) void*)(g),
        (__attribute__((address_space(3))) void*)(l),
        16, 0, 0);
}

__global__ __launch_bounds__(512, 4) void bgemm(const float* __restrict__ X,
                                                const bf16_t* __restrict__ Bt,
                                                const float* __restrict__ bias,
                                                float* __restrict__ C) {
    __shared__ __align__(16) char lds[2 * A_SLOT + 2 * B_SLOT];   // 48 KB

    const int nwg = (M_DIM / BM) * (N_DIM / BN);   // 512, %8==0
    int bid = blockIdx.x;
    int swz = (bid & 7) * (nwg >> 3) + (bid >> 3); // XCD-aware, bijective
    int tile_n = swz & 3;                          // consecutive swz share A panel
    int tile_m = swz >> 2;
    int bm0 = tile_m * BM;
    int bn0 = tile_n * BN;

    int tid = threadIdx.x;
    int w = tid >> 6, l = tid & 63;    // 8 waves: 2(M) x 4(N)
    int wr = w >> 2, wc = w & 3;       // per-wave 64x64 output
    int lr = l & 15, lk = l >> 4;

    // ---- A: thread owns row ar (0..127), 32B f32 chunk ac (0..3) ----
    int ar = tid >> 2, ac = tid & 3;
    int aslot = ac ^ ((ar >> 1) & 3);              // proven-zero write swizzle
    const float* asrc = X + (size_t)(bm0 + ar) * K_DIM + ac * 8;

    // ---- B staging: gload_lds, linear dest, pre-swizzled source (proven) ----
    int brow = tid >> 2;
    int bchk = (tid & 3) ^ ((brow >> 1) & 3);
    auto stageB = [&](int t, int c) {
        gload16(Bt + (size_t)(bn0 + c * 128 + brow) * K_DIM + t * BK + bchk * 8,
                lds + B_BASE + (t & 1) * B_SLOT + c * 8192 + tid * 16);
    };
    auto writeA = [&](int t, float4 lo, float4 hi) {   // cvt RNE + 1 ds_write_b128
        bf16x8 v;
        v[0] = (__bf16)lo.x; v[1] = (__bf16)lo.y;
        v[2] = (__bf16)lo.z; v[3] = (__bf16)lo.w;
        v[4] = (__bf16)hi.x; v[5] = (__bf16)hi.y;
        v[6] = (__bf16)hi.z; v[7] = (__bf16)hi.w;
        *(bf16x8*)(lds + (t & 1) * A_SLOT + ar * 64 + aslot * 16) = v;
    };

    f32x4 acc[4][4];
#pragma unroll
    for (int m = 0; m < 4; ++m)
#pragma unroll
        for (int n = 0; n < 4; ++n)
            acc[m][n] = (f32x4)(0.0f);

    // two named A-reg sets: A(k) lives in set k&1 (static indexing, rule #20)
    float4 aL0, aH0, aL1, aH1;

    // ---- prologue ----
    { const float4* s = (const float4*)(asrc + 0 * BK); aL0 = s[0]; aH0 = s[1]; }
    stageB(0, 0); stageB(0, 1);
    { const float4* s = (const float4*)(asrc + 1 * BK); aL1 = s[0]; aH1 = s[1]; }
    writeA(0, aL0, aH0);                       // implicit wait on A(0) regs
    asm volatile("s_waitcnt vmcnt(2)" ::: "memory");   // B(0) resident; A(1) flies
    asm volatile("s_waitcnt lgkmcnt(0)" ::: "memory"); // A(0) write visible
    __builtin_amdgcn_s_barrier();

    // ---- main loop (R14 structure; boundary fence corrected to vmcnt(2)) ----
    // per tile t: issue B(t+1), A(t+2); compute tile t; writeA(t+1) (implicit
    // vmcnt(4) on A(t+1) regs); explicit vmcnt(2) retires B(t+1) [formally
    // fences the cross-wave gload_lds->ds_read handoff], A(t+2) stays in
    // flight across the barrier (T4); lgkmcnt(0); barrier.
#define TILE_BODY(T, CUR_L, CUR_H, NXT_L, NXT_H)                                  \
    {                                                                             \
        const int t_ = (T);                                                       \
        if (t_ + 1 < NT) { stageB(t_ + 1, 0); stageB(t_ + 1, 1); }                \
        if (t_ + 2 < NT) {                                                        \
            const float4* s = (const float4*)(asrc + (t_ + 2) * BK);              \
            CUR_L = s[0]; CUR_H = s[1];        /* set (t+2)&1 == t&1 */           \
        }                                                                         \
        const char* Ab = lds + (t_ & 1) * A_SLOT;                                 \
        const char* Bb = lds + B_BASE + (t_ & 1) * B_SLOT;                        \
        bf16x8 bfr[4];                                                            \
        _Pragma("unroll") for (int n = 0; n < 4; ++n) {                           \
            int br = wc * 64 + n * 16 + lr;                                       \
            bfr[n] = *(const bf16x8*)(Bb + br * 64 + ((lk ^ ((br >> 1) & 3)) * 16)); \
        }                                                                         \
        _Pragma("unroll") for (int m = 0; m < 4; ++m) {                           \
            int r = wr * 64 + m * 16 + lr;                                        \
            bf16x8 afr = *(const bf16x8*)(Ab + r * 64 + ((lk ^ ((r >> 1) & 3)) * 16)); \
            _Pragma("unroll") for (int n = 0; n < 4; ++n)                         \
                acc[m][n] = __builtin_amdgcn_mfma_f32_16x16x32_bf16(              \
                    afr, bfr[n], acc[m][n], 0, 0, 0);                             \
        }                                                                         \
        if (t_ + 1 < NT) {                                                        \
            writeA(t_ + 1, NXT_L, NXT_H);      /* implicit vmcnt(4) on A regs */  \
            if (t_ + 2 < NT)                                                      \
                asm volatile("s_waitcnt vmcnt(2)" ::: "memory"); /* B(t+1) res. */ \
            else                                                                  \
                asm volatile("s_waitcnt vmcnt(0)" ::: "memory");                  \
            asm volatile("s_waitcnt lgkmcnt(0)" ::: "memory");                    \
            __builtin_amdgcn_s_barrier();                                         \
        }                                                                         \
    }

    for (int tt = 0; tt < NT; tt += 2) {
        TILE_BODY(tt,     aL0, aH0, aL1, aH1);   // even t: load->set0, write set1
        TILE_BODY(tt + 1, aL1, aH1, aL0, aH0);   // odd  t: load->set1, write set0
    }
#undef TILE_BODY

    // ---- epilogue: C/D layout col = lane&15, row = (lane>>4)*4 + reg ----
#pragma unroll
    for (int n = 0; n < 4; ++n) {
        int col = bn0 + wc * 64 + n * 16 + lr;
        float bv = bias[col];
#pragma unroll
        for (int m = 0; m < 4; ++m) {
            int row0 = bm0 + wr * 64 + m * 16 + lk * 4;
#pragma unroll
            for (int j = 0; j < 4; ++j)
                C[(size_t)(row0 + j) * N_DIM + col] = acc[m][n][j] + bv;
        }
    }
}

// ---------------- fallback (only if workspace too small) ----------------
__global__ void naive_bin_dense(const float* __restrict__ x,
                                const float* __restrict__ W,
                                const float* __restrict__ b,
                                float* __restrict__ out) {
    int col = blockIdx.x * 256 + threadIdx.x;
    int row = blockIdx.y;
    float acc = 0.0f;
    for (int k = 0; k < K_DIM; ++k) {
        float s = ((W[(size_t)k * N_DIM + col] + 1.0f) * 0.5f > 0.5f) ? 1.0f : -1.0f;
        acc += x[(size_t)row * K_DIM + k] * s;
    }
    out[(size_t)row * N_DIM + col] = acc + b[col];
}

extern "C" void kernel_launch(void* const* d_in, const int* in_sizes, int n_in,
                              void* d_out, int out_size, void* d_ws, size_t ws_size,
                              hipStream_t stream) {
    const float* x = (const float*)d_in[0];
    const float* W = (const float*)d_in[1];
    const float* b = (const float*)d_in[2];
    float* out = (float*)d_out;

    size_t wb_bytes = (size_t)K_DIM * N_DIM * sizeof(unsigned short);

    if (ws_size >= wb_bytes) {
        unsigned short* wbt = (unsigned short*)d_ws;
        hipLaunchKernelGGL(bin_transpose_w, dim3(N_DIM / 64, K_DIM / 64), dim3(256),
                           0, stream, W, wbt);
        hipLaunchKernelGGL(bgemm, dim3((M_DIM / BM) * (N_DIM / BN)), dim3(512), 0, stream,
                           x, (const bf16_t*)wbt, b, out);
    } else {
        hipLaunchKernelGGL(naive_bin_dense, dim3(N_DIM / 256, M_DIM), dim3(256),
                           0, stream, x, W, b, out);
    }
}